// Round 11
// baseline (485.902 us; speedup 1.0000x reference)
//
#include <hip/hip_runtime.h>

// CRF Viterbi decode (B=512, T=512, S=64).
// R10 = R9 (xor tag spaces, literal readlanes, SoA partials, lgkmcnt-only
// barrier) with TWO BATCHES PER BLOCK. 256 blocks x 4 waves; each wave runs
// batches A and B through the same structure (trans slice shared). The two
// independent per-step chains interleave in the instruction schedule, so
// batch A's LDS/barrier latency is filled by batch B's VALU work (and vice
// versa) instead of relying on co-resident blocks that stall in phase.
// Wave 0 does index-merge + backpointers + backtrace for A, wave 1 for B;
// waves 2-3 value-merge only. One barrier per step serves both batches.
// Output: out[0..B) = path_score, out[B + b*(T-1) + t] = (float)tag.

constexpr int Bz = 512;
constexpr int Tz = 512;
constexpr int Sz = 64;
constexpr float NEGINF = -10000.0f;

__device__ __forceinline__ float rlf(float x, int lane) {
    return __int_as_float(__builtin_amdgcn_readlane(__float_as_int(x), lane));
}

// Barrier waiting only on LDS ops (lgkmcnt), not vmcnt: prefetch global
// loads stay in flight across the rendezvous.
__device__ __forceinline__ void lds_barrier() {
    asm volatile("s_waitcnt lgkmcnt(0)\n\ts_barrier" ::: "memory");
}

__global__ __launch_bounds__(256)
void crf_viterbi_kernel(const float* __restrict__ logits,
                        const float* __restrict__ masks,
                        const float* __restrict__ trans,
                        float* __restrict__ out)
{
    const int n  = threadIdx.x & 63;                                  // lane id
    const int w  = __builtin_amdgcn_readfirstlane(threadIdx.x >> 6);  // wave id
    const int b0 = 2 * blockIdx.x;
    const int b1 = 2 * blockIdx.x + 1;
    const int pb = 16 * w;            // first prev of this wave's slice
    const int tg = n ^ pb;            // this lane's tag in wave-w swapped space

    __shared__ unsigned bpA[128 * 64];   // packed backpointers batch A, 32 KB
    __shared__ unsigned bpB[128 * 64];   // packed backpointers batch B, 32 KB
    __shared__ float pvalA[2][4][64], pvalB[2][4][64];
    __shared__ int   pidxA[2][4][64], pidxB[2][4][64];
    __shared__ float ysA[Tz - 1], ysB[Tz - 1];

    // transitions slice: tr[j] = trans[tg][pb + j]  (shared by both batches)
    float tr[16];
    {
        const float4* tr4 = reinterpret_cast<const float4*>(trans + tg * 64 + pb);
        #pragma unroll
        for (int k = 0; k < 4; ++k) {
            float4 t = tr4[k];
            tr[4 * k + 0] = t.x; tr[4 * k + 1] = t.y;
            tr[4 * k + 2] = t.z; tr[4 * k + 3] = t.w;
        }
    }

    float fvA = (tg == 0) ? 0.0f : NEGINF;
    float fvB = fvA;

    const float* lgbaseA = logits + (size_t)b0 * Tz * Sz;
    const float* lgbaseB = logits + (size_t)b1 * Tz * Sz;
    const float* mkbaseA = masks + (size_t)b0 * Tz;
    const float* mkbaseB = masks + (size_t)b1 * Tz;

    // group-of-4 prefetch, 2 groups deep, per batch
    float lgcA[4], lgnA[4], mkcA[4], mknA[4];
    float lgcB[4], lgnB[4], mkcB[4], mknB[4];
    #pragma unroll
    for (int k = 0; k < 4; ++k) {
        lgcA[k] = lgbaseA[(1 + k) * Sz + tg];  mkcA[k] = mkbaseA[1 + k];
        lgnA[k] = lgbaseA[(5 + k) * Sz + tg];  mknA[k] = mkbaseA[5 + k];
        lgcB[k] = lgbaseB[(1 + k) * Sz + tg];  mkcB[k] = mkbaseB[1 + k];
        lgnB[k] = lgbaseB[(5 + k) * Sz + tg];  mknB[k] = mkbaseB[5 + k];
    }

    unsigned pkA = 0, pkB = 0;
    float pscA = 0.0f, pscB = 0.0f;

    // phase-1 helper: gather own slice (literal lanes) + carry-index tree
    auto reduce16 = [&](float fv, float& mval, int& midx) {
        float v[16];
        #pragma unroll
        for (int j = 0; j < 16; ++j)
            v[j] = rlf(fv, j) + tr[j];
        float mv[8]; int mi[8];
        #pragma unroll
        for (int c = 0; c < 8; ++c) {
            bool g = v[2 * c + 1] > v[2 * c];
            mv[c] = g ? v[2 * c + 1] : v[2 * c];
            mi[c] = g ? (2 * c + 1) : (2 * c);
        }
        #pragma unroll
        for (int st = 1; st < 8; st <<= 1) {
            #pragma unroll
            for (int c = 0; c < 8; c += 2 * st) {
                bool g = mv[c + st] > mv[c];
                mv[c] = g ? mv[c + st] : mv[c];
                mi[c] = g ? mi[c + st] : mi[c];
            }
        }
        mval = mv[0]; midx = pb + mi[0];
    };

    // one dual-batch Viterbi step; k is compile-time (literal buf/lanes)
    auto step = [&](int k, float lgA, float mkA, float lgB, float mkB,
                    float& mAout, float& mBout) {
        const int buf = k & 1;
        float mvA, mvB; int miA, miB;
        reduce16(fvA, mvA, miA);
        reduce16(fvB, mvB, miB);
        pvalA[buf][w][tg] = mvA;  pidxA[buf][w][tg] = miA;
        pvalB[buf][w][tg] = mvB;  pidxB[buf][w][tg] = miB;

        lds_barrier();

        // value merges (all waves; ascending q = ascending prev, left-on-tie)
        float a0 = pvalA[buf][0][tg], a1 = pvalA[buf][1][tg];
        float a2 = pvalA[buf][2][tg], a3 = pvalA[buf][3][tg];
        float b0v = pvalB[buf][0][tg], b1v = pvalB[buf][1][tg];
        float b2v = pvalB[buf][2][tg], b3v = pvalB[buf][3][tg];

        bool ga1 = a1 > a0;   float am01 = ga1 ? a1 : a0;
        bool ga3 = a3 > a2;   float am23 = ga3 ? a3 : a2;
        bool gam = am23 > am01;
        float mA = gam ? am23 : am01;

        bool gb1 = b1v > b0v; float bm01 = gb1 ? b1v : b0v;
        bool gb3 = b3v > b2v; float bm23 = gb3 ? b3v : b2v;
        bool gbm = bm23 > bm01;
        float mB = gbm ? bm23 : bm01;

        // index merge only in the responsible wave (uniform branch)
        if (w == 0) {
            int j0 = pidxA[buf][0][tg], j1 = pidxA[buf][1][tg];
            int j2 = pidxA[buf][2][tg], j3 = pidxA[buf][3][tg];
            int k01 = ga1 ? j1 : j0;
            int k23 = ga3 ? j3 : j2;
            int gi  = gam ? k23 : k01;
            pkA |= ((unsigned)gi) << (8 * k);    // tg == n in wave 0
        } else if (w == 1) {
            int j0 = pidxB[buf][0][tg], j1 = pidxB[buf][1][tg];
            int j2 = pidxB[buf][2][tg], j3 = pidxB[buf][3][tg];
            int k01 = gb1 ? j1 : j0;
            int k23 = gb3 ? j3 : j2;
            int gi  = gbm ? k23 : k01;
            pkB |= ((unsigned)gi) << (8 * k);
        }

        fvA = mA + lgA * mkA;                    // mask multiplies emission only
        fvB = mB + lgB * mkB;
        mAout = mA; mBout = mB;
    };

    float mA, mB;

    // main: groups g = 0..126 cover steps i = 4g+k (i <= 507)
    for (int g = 0; g < 127; ++g) {
        step(0, lgcA[0], mkcA[0], lgcB[0], mkcB[0], mA, mB);
        step(1, lgcA[1], mkcA[1], lgcB[1], mkcB[1], mA, mB);
        step(2, lgcA[2], mkcA[2], lgcB[2], mkcB[2], mA, mB);
        step(3, lgcA[3], mkcA[3], lgcB[3], mkcB[3], mA, mB);

        if (w == 0) bpA[g * 64 + n] = pkA;       // identity space in wave 0
        if (w == 1) bpB[g * 64 + tg] = pkB;      // tg-addressed (covers all tags)
        pkA = 0; pkB = 0;

        // rotate prefetch; issue loads for group g+2 (rows 4g+9 .. 4g+12)
        #pragma unroll
        for (int k = 0; k < 4; ++k) {
            lgcA[k] = lgnA[k]; mkcA[k] = mknA[k];
            lgcB[k] = lgnB[k]; mkcB[k] = mknB[k];
        }
        #pragma unroll
        for (int k = 0; k < 4; ++k) {
            int t = 4 * g + 9 + k;
            t = (t < Tz) ? t : (Tz - 1);
            lgnA[k] = lgbaseA[t * Sz + tg];  mknA[k] = mkbaseA[t];
            lgnB[k] = lgbaseB[t * Sz + tg];  mknB[k] = mkbaseB[t];
        }
    }

    // tail: steps 508, 509, 510 (group 127, k = 0..2)
    step(0, lgcA[0], mkcA[0], lgcB[0], mkcB[0], mA, mB);
    step(1, lgcA[1], mkcA[1], lgcB[1], mkcB[1], mA, mB);
    step(2, lgcA[2], mkcA[2], lgcB[2], mkcB[2], mA, mB);
    pscA = mA; pscB = mB;                        // vmaxs[-1] pre-feat

    if (w == 0) {
        bpA[127 * 64 + n] = pkA;
        if (n == 63) { out[b0] = pscA; out[b1] = pscB; }  // tg==63 at n==63
    }
    if (w == 1) bpB[127 * 64 + tg] = pkB;
    __syncthreads();

    // ---- backtraces: wave 0 walks batch A, wave 1 walks batch B ----
    if (w < 2) {
        const unsigned* bp = (w == 0) ? bpA : bpB;
        float* ys = (w == 0) ? ysA : ysB;

        unsigned wcur = bp[127 * 64 + n];
        int w127_63 = __builtin_amdgcn_readlane((int)wcur, 63);
        int tag = (w127_63 >> 16) & 255;         // t0 = bptrs[510][63]

        for (int g = 127; g >= 0; --g) {
            unsigned wnext = (g > 0) ? bp[(g - 1) * 64 + n] : 0u;  // prefetch
            int smax = (g == 127) ? 2 : 3;
            for (int s = smax; s >= 0; --s) {
                int idx = 4 * g + s;
                if (n == 0) ys[idx] = (float)tag; // emit BEFORE following ptr
                int wd = __builtin_amdgcn_readlane((int)wcur, tag);
                tag = (wd >> (8 * s)) & 255;
            }
            wcur = wnext;
        }
    }
    __syncthreads();

    float* outA = out + Bz + (size_t)b0 * (Tz - 1);
    float* outB = out + Bz + (size_t)b1 * (Tz - 1);
    for (int k = threadIdx.x; k < Tz - 1; k += 256) {
        outA[k] = ysA[k];
        outB[k] = ysB[k];
    }
}

extern "C" void kernel_launch(void* const* d_in, const int* in_sizes, int n_in,
                              void* d_out, int out_size, void* d_ws, size_t ws_size,
                              hipStream_t stream) {
    const float* logits = (const float*)d_in[0];
    const float* masks  = (const float*)d_in[1];
    const float* trans  = (const float*)d_in[2];
    float* out = (float*)d_out;
    (void)in_sizes; (void)n_in; (void)out_size; (void)d_ws; (void)ws_size;

    crf_viterbi_kernel<<<dim3(Bz / 2), dim3(256), 0, stream>>>(logits, masks, trans, out);
}

// Round 12
// 342.458 us; speedup vs baseline: 1.4189x; 1.4189x over previous
//
#include <hip/hip_runtime.h>

// CRF Viterbi decode (B=512, T=512, S=64).
// R11: TAG-SPLIT, EXCHANGE-FREE step. 4 waves/block (256 thr), one batch
// per block. Wave w owns tags [16w,16w+16); lane n handles tag 16w+(n>>2),
// prev quarter q=n&3 (prevs [16q,16q+16) in-lane). Per step:
//   gather: 4x ds_read_b128 of fv quarter from double-buffered LDS fv
//           (16 lanes/addr broadcast, 2-way bank alias = free);
//   score:  16 adds vs in-register trans slice; 15-fmax balanced tree
//           (exact max) -> lane max lv;
//   64-max: quad butterfly __shfl_xor(1,2) (DPP) -> m for the tag;
//   argmax: in-lane first-index equality scan vs m, candidate
//           (lv==m)?16q+li:64, min-butterfly over quad -> global FIRST
//           argmax (exact jnp semantics: achiever with smallest prev).
//   update: fv_new = m + lg*mk, written to the other fv buffer (all quad
//           lanes, same value/addr -- 4-way write serialize ~= free);
//   ONE lds_barrier (lgkmcnt-only; prefetch loads stay in flight).
// No partial exchange, no readlanes, no index-merge. Backpointers packed
// 4 steps/dword at bp[g*64+tag] (same layout as validated R1-R10);
// backtrace = wave 0 readlane chain (bit-exact validated).
// Output: out[0..B) = path_score, out[B + b*(T-1) + t] = (float)tag.

constexpr int Bz = 512;
constexpr int Tz = 512;
constexpr int Sz = 64;
constexpr float NEGINF = -10000.0f;

// Barrier waiting only on LDS ops (lgkmcnt), not vmcnt: prefetch global
// loads stay in flight across the rendezvous. (Validated R9/R10.)
__device__ __forceinline__ void lds_barrier() {
    asm volatile("s_waitcnt lgkmcnt(0)\n\ts_barrier" ::: "memory");
}

__global__ __launch_bounds__(256)
void crf_viterbi_kernel(const float* __restrict__ logits,
                        const float* __restrict__ masks,
                        const float* __restrict__ trans,
                        float* __restrict__ out)
{
    const int n   = threadIdx.x & 63;                                 // lane id
    const int w   = __builtin_amdgcn_readfirstlane(threadIdx.x >> 6); // wave id
    const int b   = blockIdx.x;
    const int q   = n & 3;             // prev quarter this lane reduces
    const int tag = 16 * w + (n >> 2); // tag this lane computes

    __shared__ unsigned bp[128 * 64];  // packed backpointers, 32 KB
    __shared__ float fvb[2][64];       // double-buffered forward vector
    __shared__ float ys[Tz - 1];       // emitted tags (backtrace)

    // transitions slice: tr[j] = trans[tag][16q + j], j = 0..15
    float tr[16];
    {
        const float4* tr4 =
            reinterpret_cast<const float4*>(trans + tag * 64 + 16 * q);
        #pragma unroll
        for (int k = 0; k < 4; ++k) {
            float4 t = tr4[k];
            tr[4 * k + 0] = t.x; tr[4 * k + 1] = t.y;
            tr[4 * k + 2] = t.z; tr[4 * k + 3] = t.w;
        }
    }

    // init fv buffer 0
    if (threadIdx.x < 64) fvb[0][n] = (n == 0) ? 0.0f : NEGINF;

    const float* lgbase = logits + (size_t)b * Tz * Sz;
    const float* mkbase = masks + (size_t)b * Tz;

    // group-of-4 prefetch, 2 groups deep (validated R9 scheme); per-lane
    // emission for this lane's tag, uniform mask.
    float lgc[4], lgn[4], mkc[4], mkn[4];
    #pragma unroll
    for (int k = 0; k < 4; ++k) {
        lgc[k] = lgbase[(1 + k) * Sz + tag];  mkc[k] = mkbase[1 + k];
        lgn[k] = lgbase[(5 + k) * Sz + tag];  mkn[k] = mkbase[5 + k];
    }

    unsigned pk = 0;
    float psc = 0.0f;

    __syncthreads();   // fvb[0] visible

    // one Viterbi step; k compile-time => literal buffer parity
    auto step = [&](int k, float lg, float mk) -> float {
        const int rc = k & 1;            // read-buffer parity
        // gather own prev quarter (4x ds_read_b128, 16 lanes share addr)
        const float4* fv4 = reinterpret_cast<const float4*>(&fvb[rc][16 * q]);
        float4 f0 = fv4[0], f1 = fv4[1], f2 = fv4[2], f3 = fv4[3];

        float v[16];
        v[0]  = f0.x + tr[0];  v[1]  = f0.y + tr[1];
        v[2]  = f0.z + tr[2];  v[3]  = f0.w + tr[3];
        v[4]  = f1.x + tr[4];  v[5]  = f1.y + tr[5];
        v[6]  = f1.z + tr[6];  v[7]  = f1.w + tr[7];
        v[8]  = f2.x + tr[8];  v[9]  = f2.y + tr[9];
        v[10] = f2.z + tr[10]; v[11] = f2.w + tr[11];
        v[12] = f3.x + tr[12]; v[13] = f3.y + tr[13];
        v[14] = f3.z + tr[14]; v[15] = f3.w + tr[15];

        // in-lane exact max (balanced tree -> v_max3)
        float t0 = fmaxf(v[0], v[1]),   t1 = fmaxf(v[2], v[3]);
        float t2 = fmaxf(v[4], v[5]),   t3 = fmaxf(v[6], v[7]);
        float t4 = fmaxf(v[8], v[9]),   t5 = fmaxf(v[10], v[11]);
        float t6 = fmaxf(v[12], v[13]), t7 = fmaxf(v[14], v[15]);
        float u0 = fmaxf(t0, t1), u1 = fmaxf(t2, t3);
        float u2 = fmaxf(t4, t5), u3 = fmaxf(t6, t7);
        float lv = fmaxf(fmaxf(u0, u1), fmaxf(u2, u3));

        // 64-prev max for this tag: quad butterfly (lanes share tag)
        float m = fmaxf(lv, __shfl_xor(lv, 1));
        m = fmaxf(m, __shfl_xor(m, 2));

        // first-argmax: in-lane first index equal to m, then min over quad
        int li = 15;
        #pragma unroll
        for (int j = 14; j >= 0; --j) li = (v[j] == m) ? j : li;
        int cand = (lv == m) ? (16 * q + li) : 64;
        int c1 = __shfl_xor(cand, 1);  cand = (c1 < cand) ? c1 : cand;
        int c2 = __shfl_xor(cand, 2);  cand = (c2 < cand) ? c2 : cand;

        pk |= ((unsigned)cand) << (8 * k);

        float fvnew = m + lg * mk;        // mask multiplies emission only
        fvb[1 - rc][tag] = fvnew;         // all quad lanes: same value/addr

        lds_barrier();                    // the ONLY barrier per step
        return m;                         // pre-feat max (path_score)
    };

    // main: groups g = 0..126 cover steps i = 4g+k (i <= 507)
    for (int g = 0; g < 127; ++g) {
        step(0, lgc[0], mkc[0]);
        step(1, lgc[1], mkc[1]);
        step(2, lgc[2], mkc[2]);
        step(3, lgc[3], mkc[3]);

        bp[g * 64 + tag] = pk;            // all quad lanes, same value/addr
        pk = 0;

        // rotate prefetch; issue loads for group g+2 (rows 4g+9 .. 4g+12)
        #pragma unroll
        for (int k = 0; k < 4; ++k) { lgc[k] = lgn[k]; mkc[k] = mkn[k]; }
        #pragma unroll
        for (int k = 0; k < 4; ++k) {
            int t = 4 * g + 9 + k;
            t = (t < Tz) ? t : (Tz - 1);
            lgn[k] = lgbase[t * Sz + tag];
            mkn[k] = mkbase[t];
        }
    }

    // tail: steps 508 (k0), 509 (k1), 510 (k2)
    step(0, lgc[0], mkc[0]);
    psc = step(1, lgc[1], mkc[1]);        // i == 509? no: i==509 is k1? steps
    // careful: group 127 steps are i = 508+k; i == Tz-2 == 510-? Tz-2 = 510.
    // i=510 is k=2 -> psc must come from k=2's PRE-FEAT max:
    float m510 = step(2, lgc[2], mkc[2]);
    psc = m510;                           // vmaxs[-1] = step i=510 pre-feat

    bp[127 * 64 + tag] = pk;              // flush steps 508..510
    if (w == 3 && n == 63) out[b] = psc;  // tag 63: path_score = vmaxs[-1][:,63]
    __syncthreads();

    // ---- backtrace (wave 0 only; validated readlane chain) ----
    if (w == 0) {
        unsigned wcur = bp[127 * 64 + n];
        int w127_63 = __builtin_amdgcn_readlane((int)wcur, 63);
        int tg0 = (w127_63 >> 16) & 255;  // t0 = bptrs[510][63]

        int tcur = tg0;
        for (int g = 127; g >= 0; --g) {
            unsigned wnext = (g > 0) ? bp[(g - 1) * 64 + n] : 0u;  // prefetch
            int smax = (g == 127) ? 2 : 3;
            for (int s = smax; s >= 0; --s) {
                int idx = 4 * g + s;
                if (n == 0) ys[idx] = (float)tcur;  // emit BEFORE following ptr
                int wd = __builtin_amdgcn_readlane((int)wcur, tcur);
                tcur = (wd >> (8 * s)) & 255;
            }
            wcur = wnext;
        }
    }
    __syncthreads();

    float* outseq = out + Bz + (size_t)b * (Tz - 1);
    for (int k = threadIdx.x; k < Tz - 1; k += 256) outseq[k] = ys[k];
}

extern "C" void kernel_launch(void* const* d_in, const int* in_sizes, int n_in,
                              void* d_out, int out_size, void* d_ws, size_t ws_size,
                              hipStream_t stream) {
    const float* logits = (const float*)d_in[0];
    const float* masks  = (const float*)d_in[1];
    const float* trans  = (const float*)d_in[2];
    float* out = (float*)d_out;
    (void)in_sizes; (void)n_in; (void)out_size; (void)d_ws; (void)ws_size;

    crf_viterbi_kernel<<<dim3(Bz), dim3(256), 0, stream>>>(logits, masks, trans, out);
}